// Round 2
// baseline (101.590 us; speedup 1.0000x reference)
//
#include <hip/hip_runtime.h>
#include <math.h>

#define V 50257
#define E 1024
#define HH 1024
#define LL 256

// d_out layout (floats): y | h_new(2*H) | c_new(2*H) | h_t_tilde(H) | a_t(L) | p_t
#define O_H  (V)
#define O_C  (V + 2*HH)
#define O_HT (V + 4*HH)
#define O_A  (V + 5*HH)
#define O_P  (V + 5*HH + LL)

// workspace layout (floats)
#define W_T    0        // tanh(Wp@h2)        [1024]
#define W_V    1024     // h2 @ Wbil          [1024]  (atomic-accumulated)
#define W_SC   2048     // scores             [256]
#define W_CTX  2304     // context (unscaled) [1024]  (atomic-accumulated)
#define W_Z    4096     // logits             [50257]
#define W_BM   54400    // per-block max      [786]
#define W_BS   55424    // per-block sum      [786]
#define W_LOGZ 56448    // scalar

#define NB_LOGITS 786   // ceil(50257/64)

__device__ __forceinline__ float sigmoidf_(float x) { return 1.f / (1.f + expf(-x)); }

__device__ __forceinline__ float block_sum(float v, float* red) {
    int lane = threadIdx.x & 63, wv = threadIdx.x >> 6;
#pragma unroll
    for (int o = 32; o > 0; o >>= 1) v += __shfl_down(v, o, 64);
    if (lane == 0) red[wv] = v;
    __syncthreads();
    return red[0] + red[1] + red[2] + red[3];
}

// ---- LSTM cell: block u computes gate rows u, u+H, u+2H, u+3H ----
__global__ void k_lstm(const float* __restrict__ Wih, const float* __restrict__ Whh,
                       const float* __restrict__ bih, const float* __restrict__ bhh,
                       const float* __restrict__ xa_base, const int* __restrict__ tok,
                       const float* __restrict__ xb, int na, int nb,
                       const float* __restrict__ hprev, const float* __restrict__ cprev,
                       float* __restrict__ hout, float* __restrict__ cout) {
    const int u = blockIdx.x;
    const int K = na + nb;
    const float* xa = tok ? (xa_base + (size_t)tok[0] * na) : xa_base;
    const float* r0 = Wih + (size_t)u * K;
    const float* r1 = Wih + (size_t)(u + HH) * K;
    const float* r2 = Wih + (size_t)(u + 2*HH) * K;
    const float* r3 = Wih + (size_t)(u + 3*HH) * K;
    float a0 = 0, a1 = 0, a2 = 0, a3 = 0;
    for (int j = threadIdx.x; j < K; j += 256) {
        float xv = (j < na) ? xa[j] : xb[j - na];
        a0 += r0[j] * xv; a1 += r1[j] * xv; a2 += r2[j] * xv; a3 += r3[j] * xv;
    }
    const float* s0 = Whh + (size_t)u * HH;
    const float* s1 = Whh + (size_t)(u + HH) * HH;
    const float* s2 = Whh + (size_t)(u + 2*HH) * HH;
    const float* s3 = Whh + (size_t)(u + 3*HH) * HH;
    for (int j = threadIdx.x; j < HH; j += 256) {
        float hv = hprev[j];
        a0 += s0[j] * hv; a1 += s1[j] * hv; a2 += s2[j] * hv; a3 += s3[j] * hv;
    }
    int lane = threadIdx.x & 63, wv = threadIdx.x >> 6;
#pragma unroll
    for (int o = 32; o > 0; o >>= 1) {
        a0 += __shfl_down(a0, o, 64);
        a1 += __shfl_down(a1, o, 64);
        a2 += __shfl_down(a2, o, 64);
        a3 += __shfl_down(a3, o, 64);
    }
    __shared__ float sm[4][4];
    if (lane == 0) { sm[wv][0] = a0; sm[wv][1] = a1; sm[wv][2] = a2; sm[wv][3] = a3; }
    __syncthreads();
    if (threadIdx.x == 0) {
        float gi = sm[0][0]+sm[1][0]+sm[2][0]+sm[3][0] + bih[u]        + bhh[u];
        float gf = sm[0][1]+sm[1][1]+sm[2][1]+sm[3][1] + bih[u+HH]     + bhh[u+HH];
        float gg = sm[0][2]+sm[1][2]+sm[2][2]+sm[3][2] + bih[u+2*HH]   + bhh[u+2*HH];
        float go = sm[0][3]+sm[1][3]+sm[2][3]+sm[3][3] + bih[u+3*HH]   + bhh[u+3*HH];
        float c = sigmoidf_(gf) * cprev[u] + sigmoidf_(gi) * tanhf(gg);
        hout[u] = sigmoidf_(go) * tanhf(c);
        cout[u] = c;
    }
}

// ---- blocks [0,1024): t = tanh(Wp @ h2);  blocks [1024,1152): v += h2 @ Wbil tile ----
__global__ void k_ptv(const float* __restrict__ Wp, const float* __restrict__ Wbil,
                      const float* __restrict__ h2, float* __restrict__ t_out,
                      float* __restrict__ v_out) {
    __shared__ float red[4];
    if (blockIdx.x < HH) {
        int r = blockIdx.x;
        const float* row = Wp + (size_t)r * HH;
        float acc = 0;
        for (int j = threadIdx.x; j < HH; j += 256) acc += row[j] * h2[j];
        float tot = block_sum(acc, red);
        if (threadIdx.x == 0) t_out[r] = tanhf(tot);
    } else {
        int b = blockIdx.x - HH;        // 0..127
        int hc = b >> 2, kc = b & 3;    // 32 h-chunks x 4 k-chunks
        int k = kc * 256 + threadIdx.x;
        int h0 = hc * 32;
        float acc = 0;
        for (int h = h0; h < h0 + 32; ++h) acc += h2[h] * Wbil[(size_t)h * HH + k];
        atomicAdd(&v_out[k], acc);
    }
}

// ---- block 0: p_t;  blocks 1..256: score[l] = dot(v, h_s[l]) ----
__global__ void k_score_p(const float* __restrict__ wdot, const float* __restrict__ t,
                          const float* __restrict__ v, const float* __restrict__ hs,
                          float* __restrict__ score, float* __restrict__ pt) {
    __shared__ float red[4];
    if (blockIdx.x == 0) {
        float acc = 0;
        for (int j = threadIdx.x; j < HH; j += 256) acc += wdot[j] * t[j];
        float tot = block_sum(acc, red);
        if (threadIdx.x == 0) pt[0] = (float)LL * sigmoidf_(tot);
    } else {
        int l = blockIdx.x - 1;
        const float* row = hs + (size_t)l * HH;
        float acc = 0;
        for (int j = threadIdx.x; j < HH; j += 256) acc += row[j] * v[j];
        float tot = block_sum(acc, red);
        if (threadIdx.x == 0) score[l] = tot;
    }
}

// ---- single block: masked softmax + local-window reweight -> a_t ----
__global__ void k_soft(const float* __restrict__ score, const float* __restrict__ pt,
                       float* __restrict__ a_out) {
    int l = threadIdx.x;     // 256 threads = L
    float p = pt[0];
    int si = (int)rintf(p);
    int lo = max(si - 10, 0), hi = min(si + 10, LL - 1);
    bool mask = (l >= lo) && (l <= hi);
    float sc = score[l];
    __shared__ float sm[256];
    sm[l] = mask ? sc : -INFINITY;
    __syncthreads();
    for (int s = 128; s > 0; s >>= 1) { if (l < s) sm[l] = fmaxf(sm[l], sm[l + s]); __syncthreads(); }
    float M = sm[0];
    __syncthreads();
    float e = mask ? expf(sc - M) : 0.f;
    sm[l] = e;
    __syncthreads();
    for (int s = 128; s > 0; s >>= 1) { if (l < s) sm[l] += sm[l + s]; __syncthreads(); }
    float S = sm[0];
    float a = e / S;
    float d = (float)l - p;
    a_out[l] = mask ? a * expf(d * d * 0.04f) : 0.f;   // exp(+d^2/(D/2)^2), faithful
}

// ---- context (unscaled): ctx[h] += sum_l a_t[l] * h_s[l,h] ----
__global__ void k_ctx(const float* __restrict__ a_t, const float* __restrict__ hs,
                      float* __restrict__ ctx) {
    int hc = blockIdx.x & 3, lc = blockIdx.x >> 2;   // 4 h-chunks x 16 l-chunks
    int h = hc * 256 + threadIdx.x;
    int l0 = lc * 16;
    float acc = 0;
    for (int l = l0; l < l0 + 16; ++l) {
        float a = a_t[l];                             // uniform per block -> coherent skip
        if (a != 0.f) acc += a * hs[(size_t)l * HH + h];
    }
    if (acc != 0.f) atomicAdd(&ctx[h], acc);
}

// ---- h_t_tilde_new = tanh(Wcomb @ [ctx/win ; h2] + bcomb) ----
__global__ void k_comb(const float* __restrict__ Wcomb, const float* __restrict__ bcomb,
                       const float* __restrict__ ctx, const float* __restrict__ h2,
                       const float* __restrict__ pt, float* __restrict__ outv) {
    __shared__ float red[4];
    int u = blockIdx.x;
    float p = pt[0];
    int si = (int)rintf(p);
    int lo = max(si - 10, 0), hi = min(si + 10, LL - 1);
    float inv_win = 1.f / (float)(hi - lo + 1);
    const float* row = Wcomb + (size_t)u * (2 * HH);
    float acc = 0;
    for (int j = threadIdx.x; j < 2 * HH; j += 256) {
        float xv = (j < HH) ? ctx[j] * inv_win : h2[j - HH];
        acc += row[j] * xv;
    }
    float tot = block_sum(acc, red);
    if (threadIdx.x == 0) outv[u] = tanhf(tot + bcomb[u]);
}

// ---- logits: wave-per-row, 16 rows/wave, 64 rows/block; per-block online (max,sum) ----
__global__ void k_logits(const float* __restrict__ Wout, const float* __restrict__ bout,
                         const float* __restrict__ x, float* __restrict__ z,
                         float* __restrict__ bmax, float* __restrict__ bsum) {
    __shared__ float sx[1024];
    for (int j = threadIdx.x; j < 1024; j += 256) sx[j] = x[j];
    __syncthreads();
    int lane = threadIdx.x & 63, wv = threadIdx.x >> 6;
    int base = blockIdx.x * 64 + wv * 16;
    float m = -INFINITY, s = 0.f;
    for (int t = 0; t < 16; ++t) {
        int r = base + t;
        if (r >= V) break;
        const float* row = Wout + (size_t)r * 1024;
        float acc = 0;
#pragma unroll
        for (int j = 0; j < 16; ++j) acc += row[lane + 64 * j] * sx[lane + 64 * j];
#pragma unroll
        for (int o = 32; o > 0; o >>= 1) acc += __shfl_xor(acc, o, 64);
        float zz = acc + bout[r];
        if (lane == 0) z[r] = zz;
        if (zz > m) { s *= expf(m - zz); m = zz; }    // expf(-inf)=0 on first iter
        s += expf(zz - m);
    }
    __shared__ float wm[4], wsv[4];
    if (lane == 0) { wm[wv] = m; wsv[wv] = s; }
    __syncthreads();
    if (threadIdx.x == 0) {
        float M = fmaxf(fmaxf(wm[0], wm[1]), fmaxf(wm[2], wm[3]));
        float S = 0.f;
        if (M != -INFINITY) {
#pragma unroll
            for (int w = 0; w < 4; ++w)
                if (wm[w] != -INFINITY) S += wsv[w] * expf(wm[w] - M);
        }
        bmax[blockIdx.x] = M; bsum[blockIdx.x] = S;
    }
}

// ---- merge per-block (max,sum) -> logZ ----
__global__ void k_lse(const float* __restrict__ bmax, const float* __restrict__ bsum,
                      int n, float* __restrict__ logZ) {
    int tid = threadIdx.x;
    float m = -INFINITY, s = 0.f;
    for (int i = tid; i < n; i += 256) {
        float m2 = bmax[i], s2 = bsum[i];
        float M = fmaxf(m, m2);
        if (M != -INFINITY) s = s * expf(m - M) + s2 * expf(m2 - M);
        m = M;
    }
    int lane = tid & 63, wv = tid >> 6;
#pragma unroll
    for (int o = 32; o > 0; o >>= 1) {
        float m2 = __shfl_down(m, o, 64), s2 = __shfl_down(s, o, 64);
        float M = fmaxf(m, m2);
        if (M != -INFINITY) s = s * expf(m - M) + s2 * expf(m2 - M);
        else s = 0.f;
        m = M;
    }
    __shared__ float wm[4], wsv[4];
    if (lane == 0) { wm[wv] = m; wsv[wv] = s; }
    __syncthreads();
    if (tid == 0) {
        float M = -INFINITY, S = 0.f;
#pragma unroll
        for (int w = 0; w < 4; ++w) {
            float M2 = fmaxf(M, wm[w]);
            if (M2 != -INFINITY) S = S * expf(M - M2) + wsv[w] * expf(wm[w] - M2);
            M = M2;
        }
        logZ[0] = M + logf(S);
    }
}

__global__ void k_sub(const float* __restrict__ z, const float* __restrict__ logZ,
                      float* __restrict__ y) {
    int i = blockIdx.x * 256 + threadIdx.x;
    if (i < V) y[i] = z[i] - logZ[0];
}

extern "C" void kernel_launch(void* const* d_in, const int* in_sizes, int n_in,
                              void* d_out, int out_size, void* d_ws, size_t ws_size,
                              hipStream_t stream) {
    const int*   tok   = (const int*)  d_in[0];
    const float* h0    = (const float*)d_in[1];
    const float* c0    = (const float*)d_in[2];
    const float* hs    = (const float*)d_in[3];
    const float* htt   = (const float*)d_in[4];
    const float* emb   = (const float*)d_in[5];
    const float* Wp    = (const float*)d_in[6];
    const float* wdot  = (const float*)d_in[7];
    const float* Wbil  = (const float*)d_in[8];
    const float* Wcomb = (const float*)d_in[9];
    const float* bcomb = (const float*)d_in[10];
    const float* Wih0  = (const float*)d_in[11];
    const float* Whh0  = (const float*)d_in[12];
    const float* bih0  = (const float*)d_in[13];
    const float* bhh0  = (const float*)d_in[14];
    const float* Wih1  = (const float*)d_in[15];
    const float* Whh1  = (const float*)d_in[16];
    const float* bih1  = (const float*)d_in[17];
    const float* bhh1  = (const float*)d_in[18];
    const float* Wout  = (const float*)d_in[19];
    const float* bout  = (const float*)d_in[20];

    float* out = (float*)d_out;
    float* ws  = (float*)d_ws;

    float* h1o  = out + O_H;
    float* h2o  = out + O_H + HH;
    float* c1o  = out + O_C;
    float* c2o  = out + O_C + HH;
    float* htto = out + O_HT;
    float* ato  = out + O_A;
    float* pto  = out + O_P;

    // zero the atomic-accumulation regions (t/v/score/ctx)
    hipMemsetAsync(ws, 0, 3328 * sizeof(float), stream);

    hipLaunchKernelGGL(k_lstm, dim3(1024), dim3(256), 0, stream,
                       Wih0, Whh0, bih0, bhh0, emb, tok, htt, 1024, 1024,
                       h0, c0, h1o, c1o);
    hipLaunchKernelGGL(k_lstm, dim3(1024), dim3(256), 0, stream,
                       Wih1, Whh1, bih1, bhh1, h1o, (const int*)nullptr, h1o, 1024, 0,
                       h0 + HH, c0 + HH, h2o, c2o);
    hipLaunchKernelGGL(k_ptv, dim3(1024 + 128), dim3(256), 0, stream,
                       Wp, Wbil, h2o, ws + W_T, ws + W_V);
    hipLaunchKernelGGL(k_score_p, dim3(257), dim3(256), 0, stream,
                       wdot, ws + W_T, ws + W_V, hs, ws + W_SC, pto);
    hipLaunchKernelGGL(k_soft, dim3(1), dim3(256), 0, stream,
                       ws + W_SC, pto, ato);
    hipLaunchKernelGGL(k_ctx, dim3(64), dim3(256), 0, stream,
                       ato, hs, ws + W_CTX);
    hipLaunchKernelGGL(k_comb, dim3(1024), dim3(256), 0, stream,
                       Wcomb, bcomb, ws + W_CTX, h2o, pto, htto);
    hipLaunchKernelGGL(k_logits, dim3(NB_LOGITS), dim3(256), 0, stream,
                       Wout, bout, htto, ws + W_Z, ws + W_BM, ws + W_BS);
    hipLaunchKernelGGL(k_lse, dim3(1), dim3(256), 0, stream,
                       ws + W_BM, ws + W_BS, NB_LOGITS, ws + W_LOGZ);
    hipLaunchKernelGGL(k_sub, dim3((V + 255) / 256), dim3(256), 0, stream,
                       ws + W_Z, ws + W_LOGZ, out);
}

// Round 3
// 91.270 us; speedup vs baseline: 1.1131x; 1.1131x over previous
//
#include <hip/hip_runtime.h>
#include <math.h>

#define V 50257
#define E 1024
#define HH 1024
#define LL 256

// d_out layout (floats): y | h_new(2*H) | c_new(2*H) | h_t_tilde(H) | a_t(L) | p_t
#define O_H  (V)
#define O_C  (V + 2*HH)
#define O_HT (V + 4*HH)
#define O_A  (V + 5*HH)
#define O_P  (V + 5*HH + LL)

// workspace layout (floats)
#define W_T    0        // tanh(Wp@h2)        [1024]
#define W_V    1024     // h2 @ Wbil          [1024]  (atomic-accumulated; zeroed by k_lstm0)
#define W_SC   2048     // scores             [256]
#define W_CTX  2304     // context (unscaled) [1024]  (direct-stored)
#define W_Z    4096     // logits             [50257]
#define W_BM   54400    // per-block max      [786]
#define W_BS   55424    // per-block sum      [786]

#define NB_LOGITS 786   // ceil(50257/64)

__device__ __forceinline__ float sigmoidf_(float x) { return 1.f / (1.f + expf(-x)); }
__device__ __forceinline__ float dot4(float4 a, float4 b) {
    return a.x * b.x + a.y * b.y + a.z * b.z + a.w * b.w;
}

__device__ __forceinline__ float block_sum(float v, float* red) {
    int lane = threadIdx.x & 63, wv = threadIdx.x >> 6;
#pragma unroll
    for (int o = 32; o > 0; o >>= 1) v += __shfl_down(v, o, 64);
    if (lane == 0) red[wv] = v;
    __syncthreads();
    return red[0] + red[1] + red[2] + red[3];
}

// ---- LSTM cell: block u computes gate rows u, u+H, u+2H, u+3H (float4 streams) ----
__global__ void k_lstm(const float* __restrict__ Wih, const float* __restrict__ Whh,
                       const float* __restrict__ bih, const float* __restrict__ bhh,
                       const float* __restrict__ xa_base, const int* __restrict__ tok,
                       const float* __restrict__ xb, int na, int nb,
                       const float* __restrict__ hprev, const float* __restrict__ cprev,
                       float* __restrict__ hout, float* __restrict__ cout,
                       float* __restrict__ zero_buf) {
    const int u = blockIdx.x;
    const int K = na + nb;
    const int K4 = K >> 2, na4 = na >> 2;
    if (zero_buf && threadIdx.x == 0) zero_buf[u] = 0.f;   // zero W_V for k_ptv atomics
    const float* xa = tok ? (xa_base + (size_t)tok[0] * na) : xa_base;
    const float4* xa4 = (const float4*)xa;
    const float4* xb4 = (const float4*)xb;
    const float4* r0 = (const float4*)(Wih + (size_t)u * K);
    const float4* r1 = (const float4*)(Wih + (size_t)(u + HH) * K);
    const float4* r2 = (const float4*)(Wih + (size_t)(u + 2*HH) * K);
    const float4* r3 = (const float4*)(Wih + (size_t)(u + 3*HH) * K);
    float a0 = 0, a1 = 0, a2 = 0, a3 = 0;
    for (int j = threadIdx.x; j < K4; j += 256) {
        float4 xv = (j < na4) ? xa4[j] : xb4[j - na4];
        a0 += dot4(r0[j], xv); a1 += dot4(r1[j], xv);
        a2 += dot4(r2[j], xv); a3 += dot4(r3[j], xv);
    }
    const float4* s0 = (const float4*)(Whh + (size_t)u * HH);
    const float4* s1 = (const float4*)(Whh + (size_t)(u + HH) * HH);
    const float4* s2 = (const float4*)(Whh + (size_t)(u + 2*HH) * HH);
    const float4* s3 = (const float4*)(Whh + (size_t)(u + 3*HH) * HH);
    const float4* hp4 = (const float4*)hprev;
    {
        int j = threadIdx.x;           // HH/4 == 256 == blockDim
        float4 hv = hp4[j];
        a0 += dot4(s0[j], hv); a1 += dot4(s1[j], hv);
        a2 += dot4(s2[j], hv); a3 += dot4(s3[j], hv);
    }
    int lane = threadIdx.x & 63, wv = threadIdx.x >> 6;
#pragma unroll
    for (int o = 32; o > 0; o >>= 1) {
        a0 += __shfl_down(a0, o, 64);
        a1 += __shfl_down(a1, o, 64);
        a2 += __shfl_down(a2, o, 64);
        a3 += __shfl_down(a3, o, 64);
    }
    __shared__ float sm[4][4];
    if (lane == 0) { sm[wv][0] = a0; sm[wv][1] = a1; sm[wv][2] = a2; sm[wv][3] = a3; }
    __syncthreads();
    if (threadIdx.x == 0) {
        float gi = sm[0][0]+sm[1][0]+sm[2][0]+sm[3][0] + bih[u]        + bhh[u];
        float gf = sm[0][1]+sm[1][1]+sm[2][1]+sm[3][1] + bih[u+HH]     + bhh[u+HH];
        float gg = sm[0][2]+sm[1][2]+sm[2][2]+sm[3][2] + bih[u+2*HH]   + bhh[u+2*HH];
        float go = sm[0][3]+sm[1][3]+sm[2][3]+sm[3][3] + bih[u+3*HH]   + bhh[u+3*HH];
        float c = sigmoidf_(gf) * cprev[u] + sigmoidf_(gi) * tanhf(gg);
        hout[u] = sigmoidf_(go) * tanhf(c);
        cout[u] = c;
    }
}

// ---- blocks [0,1024): t = tanh(Wp @ h2);  blocks [1024,1056): v += h2 @ Wbil tile ----
__global__ void k_ptv(const float* __restrict__ Wp, const float* __restrict__ Wbil,
                      const float* __restrict__ h2, float* __restrict__ t_out,
                      float* __restrict__ v_out) {
    __shared__ float red[4];
    if (blockIdx.x < HH) {
        int r = blockIdx.x;
        const float4* row = (const float4*)(Wp + (size_t)r * HH);
        const float4* h24 = (const float4*)h2;
        float acc = dot4(row[threadIdx.x], h24[threadIdx.x]);
        float tot = block_sum(acc, red);
        if (threadIdx.x == 0) t_out[r] = tanhf(tot);
    } else {
        int b = blockIdx.x - HH;        // 0..31, h-chunk of 32 rows
        int h0 = b * 32;
        int k4 = threadIdx.x;           // float4 column slot
        const float4* W4 = (const float4*)Wbil;
        float4 acc = make_float4(0.f, 0.f, 0.f, 0.f);
        for (int h = h0; h < h0 + 32; ++h) {
            float hv = h2[h];
            float4 w = W4[(size_t)h * 256 + k4];
            acc.x += hv * w.x; acc.y += hv * w.y;
            acc.z += hv * w.z; acc.w += hv * w.w;
        }
        atomicAdd(&v_out[k4 * 4 + 0], acc.x);
        atomicAdd(&v_out[k4 * 4 + 1], acc.y);
        atomicAdd(&v_out[k4 * 4 + 2], acc.z);
        atomicAdd(&v_out[k4 * 4 + 3], acc.w);
    }
}

// ---- block 0: p_t;  blocks 1..256: score[l] = dot(v, h_s[l]) ----
__global__ void k_score_p(const float* __restrict__ wdot, const float* __restrict__ t,
                          const float* __restrict__ v, const float* __restrict__ hs,
                          float* __restrict__ score, float* __restrict__ pt) {
    __shared__ float red[4];
    if (blockIdx.x == 0) {
        const float4* w4 = (const float4*)wdot;
        const float4* t4 = (const float4*)t;
        float acc = dot4(w4[threadIdx.x], t4[threadIdx.x]);
        float tot = block_sum(acc, red);
        if (threadIdx.x == 0) pt[0] = (float)LL * sigmoidf_(tot);
    } else {
        int l = blockIdx.x - 1;
        const float4* row = (const float4*)(hs + (size_t)l * HH);
        const float4* v4  = (const float4*)v;
        float acc = dot4(row[threadIdx.x], v4[threadIdx.x]);
        float tot = block_sum(acc, red);
        if (threadIdx.x == 0) score[l] = tot;
    }
}

// ---- grid 5: softmax (redundant per block) + window-limited context / a_t write ----
__global__ void k_ctx(const float* __restrict__ score, const float* __restrict__ pt,
                      const float* __restrict__ hs, float* __restrict__ ctx,
                      float* __restrict__ a_out) {
    int l = threadIdx.x;     // 256 threads = L
    float p = pt[0];
    int si = (int)rintf(p);
    int lo = max(si - 10, 0), hi = min(si + 10, LL - 1);
    bool mask = (l >= lo) && (l <= hi);
    float sc = score[l];
    __shared__ float sm[256];
    __shared__ float sa[256];
    sm[l] = mask ? sc : -INFINITY;
    __syncthreads();
    for (int s = 128; s > 0; s >>= 1) { if (l < s) sm[l] = fmaxf(sm[l], sm[l + s]); __syncthreads(); }
    float M = sm[0];
    __syncthreads();
    float e = mask ? expf(sc - M) : 0.f;
    sm[l] = e;
    __syncthreads();
    for (int s = 128; s > 0; s >>= 1) { if (l < s) sm[l] += sm[l + s]; __syncthreads(); }
    float S = sm[0];
    float d = (float)l - p;
    sa[l] = mask ? (e / S) * expf(d * d * 0.04f) : 0.f;   // exp(+d^2/(D/2)^2), faithful
    __syncthreads();
    if (blockIdx.x == 4) {
        a_out[l] = sa[l];
    } else {
        int h = blockIdx.x * 256 + l;
        float acc = 0.f;
        for (int ll = lo; ll <= hi; ++ll)
            acc += sa[ll] * hs[(size_t)ll * HH + h];      // sa[ll]: LDS broadcast
        ctx[h] = acc;                                     // direct store, no zeroing needed
    }
}

// ---- h_t_tilde_new = tanh(Wcomb @ [ctx/win ; h2] + bcomb) ----
__global__ void k_comb(const float* __restrict__ Wcomb, const float* __restrict__ bcomb,
                       const float* __restrict__ ctx, const float* __restrict__ h2,
                       const float* __restrict__ pt, float* __restrict__ outv) {
    __shared__ float red[4];
    int u = blockIdx.x;
    float p = pt[0];
    int si = (int)rintf(p);
    int lo = max(si - 10, 0), hi = min(si + 10, LL - 1);
    float inv_win = 1.f / (float)(hi - lo + 1);
    const float4* row  = (const float4*)(Wcomb + (size_t)u * (2 * HH));
    const float4* ctx4 = (const float4*)ctx;
    const float4* h24  = (const float4*)h2;
    float acc = 0;
#pragma unroll
    for (int j = threadIdx.x; j < 512; j += 256) {
        float4 xv;
        if (j < 256) {
            xv = ctx4[j];
            xv.x *= inv_win; xv.y *= inv_win; xv.z *= inv_win; xv.w *= inv_win;
        } else {
            xv = h24[j - 256];
        }
        acc += dot4(row[j], xv);
    }
    float tot = block_sum(acc, red);
    if (threadIdx.x == 0) outv[u] = tanhf(tot + bcomb[u]);
}

// ---- logits: wave-per-row (float4), 16 rows/wave, 64 rows/block; online (max,sum) ----
__global__ void k_logits(const float* __restrict__ Wout, const float* __restrict__ bout,
                         const float* __restrict__ x, float* __restrict__ z,
                         float* __restrict__ bmax, float* __restrict__ bsum) {
    __shared__ float4 sx[256];
    sx[threadIdx.x] = ((const float4*)x)[threadIdx.x];
    __syncthreads();
    int lane = threadIdx.x & 63, wv = threadIdx.x >> 6;
    int base = blockIdx.x * 64 + wv * 16;
    float m = -INFINITY, s = 0.f;
    for (int t = 0; t < 16; ++t) {
        int r = base + t;
        if (r >= V) break;
        const float4* row = (const float4*)(Wout + (size_t)r * 1024);
        float acc = 0;
#pragma unroll
        for (int j = 0; j < 4; ++j)
            acc += dot4(row[lane + 64 * j], sx[lane + 64 * j]);
#pragma unroll
        for (int o = 32; o > 0; o >>= 1) acc += __shfl_xor(acc, o, 64);
        float zz = acc + bout[r];
        if (lane == 0) z[r] = zz;
        if (zz > m) { s *= expf(m - zz); m = zz; }    // expf(-inf)=0 on first iter
        s += expf(zz - m);
    }
    __shared__ float wm[4], wsv[4];
    if (lane == 0) { wm[wv] = m; wsv[wv] = s; }
    __syncthreads();
    if (threadIdx.x == 0) {
        float M = fmaxf(fmaxf(wm[0], wm[1]), fmaxf(wm[2], wm[3]));
        float S = 0.f;
        if (M != -INFINITY) {
#pragma unroll
            for (int w = 0; w < 4; ++w)
                if (wm[w] != -INFINITY) S += wsv[w] * expf(wm[w] - M);
        }
        bmax[blockIdx.x] = M; bsum[blockIdx.x] = S;
    }
}

// ---- fused: per-block LSE merge over (bmax,bsum) then y = z - logZ ----
__global__ void k_sub(const float* __restrict__ z, const float* __restrict__ bmax,
                      const float* __restrict__ bsum, int n, float* __restrict__ y) {
    int tid = threadIdx.x;
    float m = -INFINITY, s = 0.f;
    for (int i = tid; i < n; i += 256) {
        float m2 = bmax[i], s2 = bsum[i];
        float M = fmaxf(m, m2);
        if (M != -INFINITY) s = s * expf(m - M) + s2 * expf(m2 - M);
        m = M;
    }
    int lane = tid & 63, wv = tid >> 6;
#pragma unroll
    for (int o = 32; o > 0; o >>= 1) {
        float m2 = __shfl_down(m, o, 64), s2 = __shfl_down(s, o, 64);
        float M = fmaxf(m, m2);
        if (M != -INFINITY) s = s * expf(m - M) + s2 * expf(m2 - M);
        else s = 0.f;
        m = M;
    }
    __shared__ float wm[4], wsv[4];
    __shared__ float lzs;
    if (lane == 0) { wm[wv] = m; wsv[wv] = s; }
    __syncthreads();
    if (tid == 0) {
        float M = -INFINITY, S = 0.f;
#pragma unroll
        for (int w = 0; w < 4; ++w) {
            float M2 = fmaxf(M, wm[w]);
            if (M2 != -INFINITY) S = S * expf(M - M2) + wsv[w] * expf(wm[w] - M2);
            M = M2;
        }
        lzs = M + logf(S);
    }
    __syncthreads();
    float lz = lzs;
    int i = blockIdx.x * 256 + tid;
    if (i < V) y[i] = z[i] - lz;
}

extern "C" void kernel_launch(void* const* d_in, const int* in_sizes, int n_in,
                              void* d_out, int out_size, void* d_ws, size_t ws_size,
                              hipStream_t stream) {
    const int*   tok   = (const int*)  d_in[0];
    const float* h0    = (const float*)d_in[1];
    const float* c0    = (const float*)d_in[2];
    const float* hs    = (const float*)d_in[3];
    const float* htt   = (const float*)d_in[4];
    const float* emb   = (const float*)d_in[5];
    const float* Wp    = (const float*)d_in[6];
    const float* wdot  = (const float*)d_in[7];
    const float* Wbil  = (const float*)d_in[8];
    const float* Wcomb = (const float*)d_in[9];
    const float* bcomb = (const float*)d_in[10];
    const float* Wih0  = (const float*)d_in[11];
    const float* Whh0  = (const float*)d_in[12];
    const float* bih0  = (const float*)d_in[13];
    const float* bhh0  = (const float*)d_in[14];
    const float* Wih1  = (const float*)d_in[15];
    const float* Whh1  = (const float*)d_in[16];
    const float* bih1  = (const float*)d_in[17];
    const float* bhh1  = (const float*)d_in[18];
    const float* Wout  = (const float*)d_in[19];
    const float* bout  = (const float*)d_in[20];

    float* out = (float*)d_out;
    float* ws  = (float*)d_ws;

    float* h1o  = out + O_H;
    float* h2o  = out + O_H + HH;
    float* c1o  = out + O_C;
    float* c2o  = out + O_C + HH;
    float* htto = out + O_HT;
    float* ato  = out + O_A;
    float* pto  = out + O_P;

    hipLaunchKernelGGL(k_lstm, dim3(1024), dim3(256), 0, stream,
                       Wih0, Whh0, bih0, bhh0, emb, tok, htt, 1024, 1024,
                       h0, c0, h1o, c1o, ws + W_V);
    hipLaunchKernelGGL(k_lstm, dim3(1024), dim3(256), 0, stream,
                       Wih1, Whh1, bih1, bhh1, h1o, (const int*)nullptr, h1o, 1024, 0,
                       h0 + HH, c0 + HH, h2o, c2o, (float*)nullptr);
    hipLaunchKernelGGL(k_ptv, dim3(1024 + 32), dim3(256), 0, stream,
                       Wp, Wbil, h2o, ws + W_T, ws + W_V);
    hipLaunchKernelGGL(k_score_p, dim3(257), dim3(256), 0, stream,
                       wdot, ws + W_T, ws + W_V, hs, ws + W_SC, pto);
    hipLaunchKernelGGL(k_ctx, dim3(5), dim3(256), 0, stream,
                       ws + W_SC, pto, hs, ws + W_CTX, ato);
    hipLaunchKernelGGL(k_comb, dim3(1024), dim3(256), 0, stream,
                       Wcomb, bcomb, ws + W_CTX, h2o, pto, htto);
    hipLaunchKernelGGL(k_logits, dim3(NB_LOGITS), dim3(256), 0, stream,
                       Wout, bout, htto, ws + W_Z, ws + W_BM, ws + W_BS);
    hipLaunchKernelGGL(k_sub, dim3((V + 255) / 256), dim3(256), 0, stream,
                       ws + W_Z, ws + W_BM, ws + W_BS, NB_LOGITS, out);
}